// Round 10
// baseline (255.568 us; speedup 1.0000x reference)
//
#include <hip/hip_runtime.h>
#include <stdint.h>

// SynapticSNN — fp32 problem. cur1 = X@W1^T + b1 fp32 (bf16 amplifies ~67x
// through the recurrence -> spike flips). Recurrence: EXACT np fp32 op order,
// scalar __f*_rn only. *** PACKED fp32 (v_pk_*) IS BANNED: R9 A/B showed it
// flips a final spike (absmax 0.086 > 0.068) while RA/scheduling-only changes
// (R4-R6) preserved absmax to the bit. *** GEMM2 via bf16 MFMA (final op,
// unamplified; bf16-W2 noise 0.0156 vs 0.068 threshold).
// R10: k1 = R8-exact arithmetic, only launch_bounds (256,4)->(256,8)
// (RA-only: cap 64 regs incl any AGPR padding -> 8 waves/SIMD residency;
// arch VGPR use was 48, so no spill expected). k2 = R9's 64-row shape
// (bit-identical partials, 2 blocks/CU).

typedef __attribute__((ext_vector_type(8))) short short8;
typedef __attribute__((ext_vector_type(4))) float floatx4;

#define NSTEPS 100

static __device__ __forceinline__ uint32_t f2bf2(float lo, float hi) {
  union { float f; uint32_t u; } a, b; a.f = lo; b.f = hi;
  uint32_t x = (a.u + 0x7FFFu + ((a.u >> 16) & 1u)) >> 16;
  uint32_t y = (b.u + 0x7FFFu + ((b.u >> 16) & 1u)) & 0xFFFF0000u;
  return x | y;
}

// ---------------------------------------------------------------------------
// Kernel 1 (R8-exact arithmetic): GEMM1 64x64 tile 4x4/thread BK=32 +
// scalar-rn recurrence. spk (bf16 {0,1}) [4096,2048] -> ws.
// ---------------------------------------------------------------------------
__global__ __launch_bounds__(256, 8) void snn_k1(
    const float* __restrict__ X, const float* __restrict__ W1,
    const float* __restrict__ b1, const float* __restrict__ betap,
    uint16_t* __restrict__ spk)
{
  __shared__ __align__(16) float As[32 * 68];
  __shared__ __align__(16) float Bs[32 * 68];
  const int tid = threadIdx.x;
  const int bm  = blockIdx.y * 64;   // batch rows
  const int bn  = blockIdx.x * 64;   // hidden cols
  const int ty  = tid >> 4;          // 0..15
  const int tx  = tid & 15;          // 0..15
  const int sc  = tid & 7;           // staging k-group (4 floats)
  const int sr  = tid >> 3;          // staging row 0..31

  float acc[4][4] = {};

  float4 xa[2], wa[2];
  #pragma unroll
  for (int h = 0; h < 2; ++h) {
    const int r = sr + h * 32;
    xa[h] = *(const float4*)(X  + (size_t)(bm + r) * 256 + sc * 4);
    wa[h] = *(const float4*)(W1 + (size_t)(bn + r) * 256 + sc * 4);
  }

  #pragma unroll 1
  for (int k0 = 0; k0 < 256; k0 += 32) {
    #pragma unroll
    for (int h = 0; h < 2; ++h) {
      const int r = sr + h * 32;
      As[(sc * 4 + 0) * 68 + r] = xa[h].x;
      As[(sc * 4 + 1) * 68 + r] = xa[h].y;
      As[(sc * 4 + 2) * 68 + r] = xa[h].z;
      As[(sc * 4 + 3) * 68 + r] = xa[h].w;
      Bs[(sc * 4 + 0) * 68 + r] = wa[h].x;
      Bs[(sc * 4 + 1) * 68 + r] = wa[h].y;
      Bs[(sc * 4 + 2) * 68 + r] = wa[h].z;
      Bs[(sc * 4 + 3) * 68 + r] = wa[h].w;
    }
    __syncthreads();

    if (k0 < 224) {
      const int kn = k0 + 32;
      #pragma unroll
      for (int h = 0; h < 2; ++h) {
        const int r = sr + h * 32;
        xa[h] = *(const float4*)(X  + (size_t)(bm + r) * 256 + kn + sc * 4);
        wa[h] = *(const float4*)(W1 + (size_t)(bn + r) * 256 + kn + sc * 4);
      }
    }

    #pragma unroll
    for (int kk = 0; kk < 32; ++kk) {
      const float4 a4 = *(const float4*)(As + kk * 68 + ty * 4);
      const float4 b4 = *(const float4*)(Bs + kk * 68 + tx * 4);
      const float av[4] = {a4.x, a4.y, a4.z, a4.w};
      const float bv[4] = {b4.x, b4.y, b4.z, b4.w};
      #pragma unroll
      for (int i = 0; i < 4; ++i)
        #pragma unroll
        for (int j = 0; j < 4; ++j)
          acc[i][j] += av[i] * bv[j];
    }
    __syncthreads();
  }

  float beta = betap[0];
  beta = fminf(fmaxf(beta, 0.0f), 1.0f);
  float bias[4];
  #pragma unroll
  for (int j = 0; j < 4; ++j) bias[j] = b1[bn + tx * 4 + j];

  float cc[16];
  #pragma unroll
  for (int i = 0; i < 4; ++i)
    #pragma unroll
    for (int j = 0; j < 4; ++j)
      cc[i * 4 + j] = acc[i][j] + bias[j];

  #pragma unroll
  for (int h = 0; h < 2; ++h) {
    float syn[8], mem[8];
    #pragma unroll
    for (int e = 0; e < 8; ++e) { syn[e] = 0.0f; mem[e] = 0.0f; }

    #pragma unroll 1
    for (int t = 0; t < NSTEPS; ++t) {
      #pragma unroll
      for (int e = 0; e < 8; ++e) {
        const float rst = (mem[e] > 1.0f) ? 1.0f : 0.0f;   // pre-update reset
        syn[e] = __fadd_rn(__fmul_rn(0.9f, syn[e]), cc[h * 8 + e]);
        mem[e] = __fsub_rn(__fadd_rn(__fmul_rn(beta, mem[e]), syn[e]), rst);
      }
    }

    #pragma unroll
    for (int i = 0; i < 2; ++i) {
      ushort4 o;
      o.x = (mem[i * 4 + 0] > 1.0f) ? (uint16_t)0x3F80u : (uint16_t)0u;
      o.y = (mem[i * 4 + 1] > 1.0f) ? (uint16_t)0x3F80u : (uint16_t)0u;
      o.z = (mem[i * 4 + 2] > 1.0f) ? (uint16_t)0x3F80u : (uint16_t)0u;
      o.w = (mem[i * 4 + 3] > 1.0f) ? (uint16_t)0x3F80u : (uint16_t)0u;
      *(ushort4*)(spk + (size_t)(bm + ty * 4 + h * 2 + i) * 2048 + bn + tx * 4) = o;
    }
  }
}

// ---------------------------------------------------------------------------
// Kernel 2: spk[4096,2048](bf16) @ W2[128,2048]^T via 16x16x32 bf16 MFMA.
// 64m x 128n tiles, split-K=8 (K-chunk 256, BK=64). Grid (64, 8) = 512
// blocks = 2/CU. Wave w covers n = w*32..+31, all 64 m rows. Per-element
// K-chain (kc->kk->ks->MFMA) identical to the R8-validated kernel ->
// bit-identical partials. W2 fp32->bf16 (rne) in-register. LDS stride 72
// shorts (2-way bank aliasing = free).
// ---------------------------------------------------------------------------
#define PS 72

__global__ __launch_bounds__(256) void snn_k2(
    const uint16_t* __restrict__ spk, const float* __restrict__ W2,
    float* __restrict__ part)
{
  __shared__ short As[64 * PS];
  __shared__ short Bs[128 * PS];
  const int tid  = threadIdx.x;
  const int lane = tid & 63;
  const int w    = tid >> 6;
  const int wn   = w * 32;
  const int bm   = blockIdx.x * 64;
  const int kc   = blockIdx.y;          // K chunk of 256

  floatx4 acc[4][2] = {};

  #pragma unroll 1
  for (int kk = 0; kk < 4; ++kk) {
    const int k0 = kc * 256 + kk * 64;
    #pragma unroll
    for (int p = 0; p < 2; ++p) {
      const int u = p * 256 + tid;
      const int r = u >> 3, c = u & 7;
      const int4 va = *(const int4*)(spk + (size_t)(bm + r) * 2048 + k0 + c * 8);
      *(int4*)(As + r * PS + c * 8) = va;
    }
    #pragma unroll
    for (int p = 0; p < 4; ++p) {
      const int u = p * 256 + tid;
      const int n = u >> 3, c = u & 7;
      const float* wp = W2 + (size_t)n * 2048 + k0 + c * 8;
      const float4 w0 = *(const float4*)(wp);
      const float4 w1 = *(const float4*)(wp + 4);
      int4 pk;
      pk.x = (int)f2bf2(w0.x, w0.y);
      pk.y = (int)f2bf2(w0.z, w0.w);
      pk.z = (int)f2bf2(w1.x, w1.y);
      pk.w = (int)f2bf2(w1.z, w1.w);
      *(int4*)(Bs + n * PS + c * 8) = pk;
    }
    __syncthreads();

    #pragma unroll
    for (int ks = 0; ks < 2; ++ks) {
      const int kb = ks * 4 + (lane >> 4);   // k-chunk 0..7
      const int fe = lane & 15;
      short8 a8[4], b8[2];
      #pragma unroll
      for (int tm = 0; tm < 4; ++tm)
        a8[tm] = *(const short8*)(As + (tm * 16 + fe) * PS + kb * 8);
      #pragma unroll
      for (int tn = 0; tn < 2; ++tn)
        b8[tn] = *(const short8*)(Bs + (wn + tn * 16 + fe) * PS + kb * 8);
      #pragma unroll
      for (int tm = 0; tm < 4; ++tm)
        #pragma unroll
        for (int tn = 0; tn < 2; ++tn)
          acc[tm][tn] = __builtin_amdgcn_mfma_f32_16x16x32_bf16(
              a8[tm], b8[tn], acc[tm][tn], 0, 0, 0);
    }
    __syncthreads();
  }

  const int fe = lane & 15;
  const int fr = (lane >> 4) * 4;   // C/D: col=lane&15, row=quad*4+reg
  #pragma unroll
  for (int tm = 0; tm < 4; ++tm)
    #pragma unroll
    for (int tn = 0; tn < 2; ++tn)
      #pragma unroll
      for (int r = 0; r < 4; ++r) {
        const int row = bm + tm * 16 + fr + r;
        const int col = wn + tn * 16 + fe;
        part[((size_t)kc * 4096 + row) * 128 + col] = acc[tm][tn][r];
      }
}

// ---------------------------------------------------------------------------
// Kernel 3: out[m][n] = sum_kc part[kc][m][n] + b2[n]  (fp32 out)
// ---------------------------------------------------------------------------
__global__ __launch_bounds__(256) void snn_k3(
    const float* __restrict__ part, const float* __restrict__ b2,
    float* __restrict__ out)
{
  const int idx = blockIdx.x * 256 + threadIdx.x;
  const int m = idx >> 5;
  const int c = (idx & 31) << 2;
  float s0 = 0.f, s1 = 0.f, s2 = 0.f, s3 = 0.f;
  #pragma unroll
  for (int kc = 0; kc < 8; ++kc) {
    const float4 p = *(const float4*)(part + ((size_t)kc * 4096 + m) * 128 + c);
    s0 += p.x; s1 += p.y; s2 += p.z; s3 += p.w;
  }
  float4 o;
  o.x = s0 + b2[c + 0];
  o.y = s1 + b2[c + 1];
  o.z = s2 + b2[c + 2];
  o.w = s3 + b2[c + 3];
  *(float4*)(out + (size_t)m * 128 + c) = o;
}

extern "C" void kernel_launch(void* const* d_in, const int* in_sizes, int n_in,
                              void* d_out, int out_size, void* d_ws, size_t ws_size,
                              hipStream_t stream) {
  const float* X    = (const float*)d_in[0];  // [4096,256]
  const float* W1   = (const float*)d_in[1];  // [2048,256]
  const float* b1   = (const float*)d_in[2];  // [2048]
  const float* W2   = (const float*)d_in[3];  // [128,2048]
  const float* b2   = (const float*)d_in[4];  // [128]
  const float* beta = (const float*)d_in[5];  // scalar
  float* out = (float*)d_out;                 // [4096,128] fp32

  uint16_t* spk = (uint16_t*)d_ws;                               // 16 MiB
  float* part = (float*)((char*)d_ws + (size_t)4096 * 2048 * 2); // 16 MiB

  snn_k1<<<dim3(32, 64), 256, 0, stream>>>(X, W1, b1, beta, spk);
  snn_k2<<<dim3(64, 8), 256, 0, stream>>>(spk, W2, part);
  snn_k3<<<512, 256, 0, stream>>>(part, b2, out);
}

// Round 11
// 226.923 us; speedup vs baseline: 1.1262x; 1.1262x over previous
//
#include <hip/hip_runtime.h>
#include <stdint.h>

// SynapticSNN — fp32 problem. cur1 = X@W1^T + b1 fp32 (bf16 amplifies ~67x
// through the recurrence -> spike flips). Recurrence: EXACT np fp32 op order,
// scalar __f*_rn only. BANNED: packed v_pk_* fp32 in the recurrence (R9:
// flips a spike); launch_bounds min-waves > 4 (R10: VGPR 32 -> 190 MB scratch
// spill). GEMM2 via bf16 MFMA (final op, unamplified; noise 0.0156 < 0.068).
// R11 theory: k1's GEMM phase was LDS-BW-bound (4x4 tiles = 2 B/FMA; 24.7k
// LDS-cyc vs 8.2k VALU-cyc per block; lockstep phases -> 82+75 = 157 us
// matches measured 160). Fix: 128x128 tile, 8x8/thread split-quadrant
// -> 1 B/FMA. Per-element fmac chain (k ascending) unchanged -> bit-identical
// spikes. k2/k3 = R8 verbatim (tail 54 us validated, absmax 0.015625).

typedef __attribute__((ext_vector_type(8))) short short8;
typedef __attribute__((ext_vector_type(4))) float floatx4;

#define NSTEPS 100

static __device__ __forceinline__ uint32_t f2bf2(float lo, float hi) {
  union { float f; uint32_t u; } a, b; a.f = lo; b.f = hi;
  uint32_t x = (a.u + 0x7FFFu + ((a.u >> 16) & 1u)) >> 16;
  uint32_t y = (b.u + 0x7FFFu + ((b.u >> 16) & 1u)) & 0xFFFF0000u;
  return x | y;
}

// ---------------------------------------------------------------------------
// Kernel 1: GEMM1 128x128 tile, 16x16 threads, 8x8/thread (quadrant split:
// rows ty*4..+3 and 64+ty*4..+3; cols tx*4..+3 and 64+tx*4..+3), BK=32,
// LDS [kk][row] stride 132. Then scalar-rn recurrence in 8 passes of 8.
// spk (bf16 {0,1}) [4096,2048] -> ws.
// ---------------------------------------------------------------------------
__global__ __launch_bounds__(256, 4) void snn_k1(
    const float* __restrict__ X, const float* __restrict__ W1,
    const float* __restrict__ b1, const float* __restrict__ betap,
    uint16_t* __restrict__ spk)
{
  __shared__ __align__(16) float As[32 * 132];
  __shared__ __align__(16) float Bs[32 * 132];
  const int tid = threadIdx.x;
  const int bm  = blockIdx.y * 128;  // batch rows
  const int bn  = blockIdx.x * 128;  // hidden cols
  const int ty  = tid >> 4;          // 0..15
  const int tx  = tid & 15;          // 0..15
  const int sc  = tid & 7;           // staging k-group (4 floats)
  const int sr  = tid >> 3;          // staging row 0..31

  float acc[8][8] = {};   // [r8][c8]; r<4 -> row ty*4+r, r>=4 -> 64+ty*4+(r-4)

  #pragma unroll 1
  for (int k0 = 0; k0 < 256; k0 += 32) {
    #pragma unroll
    for (int p = 0; p < 4; ++p) {
      const int r = p * 32 + sr;
      const float4 xa = *(const float4*)(X  + (size_t)(bm + r) * 256 + k0 + sc * 4);
      const float4 wa = *(const float4*)(W1 + (size_t)(bn + r) * 256 + k0 + sc * 4);
      As[(sc * 4 + 0) * 132 + r] = xa.x;
      As[(sc * 4 + 1) * 132 + r] = xa.y;
      As[(sc * 4 + 2) * 132 + r] = xa.z;
      As[(sc * 4 + 3) * 132 + r] = xa.w;
      Bs[(sc * 4 + 0) * 132 + r] = wa.x;
      Bs[(sc * 4 + 1) * 132 + r] = wa.y;
      Bs[(sc * 4 + 2) * 132 + r] = wa.z;
      Bs[(sc * 4 + 3) * 132 + r] = wa.w;
    }
    __syncthreads();
    #pragma unroll
    for (int kk = 0; kk < 32; ++kk) {
      const float4 al = *(const float4*)(As + kk * 132 + ty * 4);
      const float4 ah = *(const float4*)(As + kk * 132 + 64 + ty * 4);
      const float4 bl = *(const float4*)(Bs + kk * 132 + tx * 4);
      const float4 bh = *(const float4*)(Bs + kk * 132 + 64 + tx * 4);
      const float av[8] = {al.x, al.y, al.z, al.w, ah.x, ah.y, ah.z, ah.w};
      const float bv[8] = {bl.x, bl.y, bl.z, bl.w, bh.x, bh.y, bh.z, bh.w};
      #pragma unroll
      for (int i = 0; i < 8; ++i)
        #pragma unroll
        for (int j = 0; j < 8; ++j)
          acc[i][j] += av[i] * bv[j];
    }
    __syncthreads();
  }

  // ---- recurrence: np fp32 semantics, scalar __f*_rn, 8 passes of 8 ----
  float beta = betap[0];
  beta = fminf(fmaxf(beta, 0.0f), 1.0f);
  float bias[8];
  #pragma unroll
  for (int j = 0; j < 4; ++j) {
    bias[j]     = b1[bn + tx * 4 + j];
    bias[4 + j] = b1[bn + 64 + tx * 4 + j];
  }

  float cc[64];
  #pragma unroll
  for (int i = 0; i < 8; ++i)
    #pragma unroll
    for (int j = 0; j < 8; ++j)
      cc[i * 8 + j] = acc[i][j] + bias[j];

  #pragma unroll
  for (int p = 0; p < 8; ++p) {        // pass p = one output row, 8 cols
    float syn[8], mem[8];
    #pragma unroll
    for (int e = 0; e < 8; ++e) { syn[e] = 0.0f; mem[e] = 0.0f; }

    #pragma unroll 1
    for (int t = 0; t < NSTEPS; ++t) {
      #pragma unroll
      for (int e = 0; e < 8; ++e) {
        const float rst = (mem[e] > 1.0f) ? 1.0f : 0.0f;   // pre-update reset
        syn[e] = __fadd_rn(__fmul_rn(0.9f, syn[e]), cc[p * 8 + e]);
        mem[e] = __fsub_rn(__fadd_rn(__fmul_rn(beta, mem[e]), syn[e]), rst);
      }
    }

    const int row = bm + ((p < 4) ? (ty * 4 + p) : (64 + ty * 4 + (p - 4)));
    ushort4 olo, ohi;
    olo.x = (mem[0] > 1.0f) ? (uint16_t)0x3F80u : (uint16_t)0u;
    olo.y = (mem[1] > 1.0f) ? (uint16_t)0x3F80u : (uint16_t)0u;
    olo.z = (mem[2] > 1.0f) ? (uint16_t)0x3F80u : (uint16_t)0u;
    olo.w = (mem[3] > 1.0f) ? (uint16_t)0x3F80u : (uint16_t)0u;
    ohi.x = (mem[4] > 1.0f) ? (uint16_t)0x3F80u : (uint16_t)0u;
    ohi.y = (mem[5] > 1.0f) ? (uint16_t)0x3F80u : (uint16_t)0u;
    ohi.z = (mem[6] > 1.0f) ? (uint16_t)0x3F80u : (uint16_t)0u;
    ohi.w = (mem[7] > 1.0f) ? (uint16_t)0x3F80u : (uint16_t)0u;
    *(ushort4*)(spk + (size_t)row * 2048 + bn + tx * 4)      = olo;
    *(ushort4*)(spk + (size_t)row * 2048 + bn + 64 + tx * 4) = ohi;
  }
}

// ---------------------------------------------------------------------------
// Kernel 2 (R8 verbatim): spk[4096,2048](bf16) @ W2[128,2048]^T via
// 16x16x32 bf16 MFMA. 128m x 128n tiles, split-K=8, grid (32, 8).
// W2 fp32 -> bf16 (rne) in-register. LDS stride 72 shorts (2-way = free).
// ---------------------------------------------------------------------------
#define PS 72

__global__ __launch_bounds__(256) void snn_k2(
    const uint16_t* __restrict__ spk, const float* __restrict__ W2,
    float* __restrict__ part)
{
  __shared__ short As[128 * PS];
  __shared__ short Bs[128 * PS];
  const int tid  = threadIdx.x;
  const int lane = tid & 63;
  const int w    = tid >> 6;
  const int wm   = (w >> 1) * 64;
  const int wn   = (w & 1) * 64;
  const int bm   = blockIdx.x * 128;
  const int kc   = blockIdx.y;          // K chunk of 256

  floatx4 acc[4][4] = {};

  #pragma unroll 1
  for (int kk = 0; kk < 4; ++kk) {
    const int k0 = kc * 256 + kk * 64;
    #pragma unroll
    for (int p = 0; p < 4; ++p) {
      const int u = p * 256 + tid;
      const int r = u >> 3, c = u & 7;
      const int4 va = *(const int4*)(spk + (size_t)(bm + r) * 2048 + k0 + c * 8);
      *(int4*)(As + r * PS + c * 8) = va;
    }
    #pragma unroll
    for (int p = 0; p < 4; ++p) {
      const int u = p * 256 + tid;
      const int n = u >> 3, c = u & 7;
      const float* wp = W2 + (size_t)n * 2048 + k0 + c * 8;
      const float4 w0 = *(const float4*)(wp);
      const float4 w1 = *(const float4*)(wp + 4);
      int4 pk;
      pk.x = (int)f2bf2(w0.x, w0.y);
      pk.y = (int)f2bf2(w0.z, w0.w);
      pk.z = (int)f2bf2(w1.x, w1.y);
      pk.w = (int)f2bf2(w1.z, w1.w);
      *(int4*)(Bs + n * PS + c * 8) = pk;
    }
    __syncthreads();

    #pragma unroll
    for (int ks = 0; ks < 2; ++ks) {
      const int kb = ks * 4 + (lane >> 4);   // k-chunk 0..7
      const int fe = lane & 15;
      short8 a8[4], b8[4];
      #pragma unroll
      for (int tm = 0; tm < 4; ++tm)
        a8[tm] = *(const short8*)(As + (wm + tm * 16 + fe) * PS + kb * 8);
      #pragma unroll
      for (int tn = 0; tn < 4; ++tn)
        b8[tn] = *(const short8*)(Bs + (wn + tn * 16 + fe) * PS + kb * 8);
      #pragma unroll
      for (int tm = 0; tm < 4; ++tm)
        #pragma unroll
        for (int tn = 0; tn < 4; ++tn)
          acc[tm][tn] = __builtin_amdgcn_mfma_f32_16x16x32_bf16(
              a8[tm], b8[tn], acc[tm][tn], 0, 0, 0);
    }
    __syncthreads();
  }

  const int fe = lane & 15;
  const int fr = (lane >> 4) * 4;   // C/D: col=lane&15, row=quad*4+reg
  #pragma unroll
  for (int tm = 0; tm < 4; ++tm)
    #pragma unroll
    for (int tn = 0; tn < 4; ++tn)
      #pragma unroll
      for (int r = 0; r < 4; ++r) {
        const int row = bm + wm + tm * 16 + fr + r;
        const int col = wn + tn * 16 + fe;
        part[((size_t)kc * 4096 + row) * 128 + col] = acc[tm][tn][r];
      }
}

// ---------------------------------------------------------------------------
// Kernel 3: out[m][n] = sum_kc part[kc][m][n] + b2[n]  (fp32 out)
// ---------------------------------------------------------------------------
__global__ __launch_bounds__(256) void snn_k3(
    const float* __restrict__ part, const float* __restrict__ b2,
    float* __restrict__ out)
{
  const int idx = blockIdx.x * 256 + threadIdx.x;
  const int m = idx >> 5;
  const int c = (idx & 31) << 2;
  float s0 = 0.f, s1 = 0.f, s2 = 0.f, s3 = 0.f;
  #pragma unroll
  for (int kc = 0; kc < 8; ++kc) {
    const float4 p = *(const float4*)(part + ((size_t)kc * 4096 + m) * 128 + c);
    s0 += p.x; s1 += p.y; s2 += p.z; s3 += p.w;
  }
  float4 o;
  o.x = s0 + b2[c + 0];
  o.y = s1 + b2[c + 1];
  o.z = s2 + b2[c + 2];
  o.w = s3 + b2[c + 3];
  *(float4*)(out + (size_t)m * 128 + c) = o;
}

extern "C" void kernel_launch(void* const* d_in, const int* in_sizes, int n_in,
                              void* d_out, int out_size, void* d_ws, size_t ws_size,
                              hipStream_t stream) {
  const float* X    = (const float*)d_in[0];  // [4096,256]
  const float* W1   = (const float*)d_in[1];  // [2048,256]
  const float* b1   = (const float*)d_in[2];  // [2048]
  const float* W2   = (const float*)d_in[3];  // [128,2048]
  const float* b2   = (const float*)d_in[4];  // [128]
  const float* beta = (const float*)d_in[5];  // scalar
  float* out = (float*)d_out;                 // [4096,128] fp32

  uint16_t* spk = (uint16_t*)d_ws;                               // 16 MiB
  float* part = (float*)((char*)d_ws + (size_t)4096 * 2048 * 2); // 16 MiB

  snn_k1<<<dim3(16, 32), 256, 0, stream>>>(X, W1, b1, beta, spk);
  snn_k2<<<dim3(32, 8), 256, 0, stream>>>(spk, W2, part);
  snn_k3<<<512, 256, 0, stream>>>(part, b2, out);
}